// Round 9
// baseline (121.035 us; speedup 1.0000x reference)
//
#include <hip/hip_runtime.h>

#define HH 512
#define IND 13
#define NN 2048
#define RR 256
#define WDIM 7168      // (13+1)*512
#define W1DIM 6656     // 13*512
#define XTILE 512      // n per block
#define NTHREADS 256
#define NEG_HALF_LOG_2PI (-0.91893853320467274f)

typedef __attribute__((ext_vector_type(8))) short short8;   // 8 bf16 (4 VGPRs) MFMA A/B frag
typedef __attribute__((ext_vector_type(4))) float f32x4;    // MFMA C/D frag

// fp32 -> bf16 round-to-nearest-even (bit pattern)
__device__ __forceinline__ short f2bf(float f) {
    unsigned u = __float_as_uint(f);
    u += 0x7fffu + ((u >> 16) & 1u);
    return (short)(u >> 16);
}
__device__ __forceinline__ float bf2f(short s) {
    return __uint_as_float(((unsigned)(unsigned short)s) << 16);
}

// Per block: one r, 512 n (4 waves x 128 n). Per wave: 32 h-tiles x 8 n-tiles of
// 16x16x32 bf16 MFMA, hidden stays in C-frags, relu+w2-dot in fp32 VALU.
// K packing: A = [w1(13) | w1(13) | 0(6)], B = [x_hi(13) | x_lo(13) | 0(6)]
// => hidden = w1_bf16 . x_fp32 (x split exact); only w1 carries bf16 rounding.
// R9 delta vs green R8 (PROLOGUE ONLY): x is staged into LDS in MFMA-ready
// row layout by a divergence-free cooperative loop; the old 4-way q-divergent
// in-register bfrag build (the VALU hot spot per R8 counters) becomes
// 8 broadcast ds_read_b128 per wave. Staged values bitwise-identical.
// Main loop / reduction / epilogue / grid / launch_bounds: unchanged.
__global__ __launch_bounds__(NTHREADS, 3)
void ffrelu_mfma_kernel(const float* __restrict__ x,
                        const float* __restrict__ y,
                        const float* __restrict__ w,
                        float* __restrict__ out) {
    __shared__ short Als[HH * 32];     // 32768 B: w1 rows [w1|w1|0], 64 B stride
    __shared__ short xls[XTILE * 32];  // 32768 B: x rows [hi|lo|0], 64 B stride
    __shared__ float w2s[HH];          // 2048 B, fp32

    const int tid = threadIdx.x;
    const int r = blockIdx.y;
    const int wave = tid >> 6;
    const int lane = tid & 63;
    const int m = lane & 15;        // MFMA row/col index within 16
    const int q = lane >> 4;        // quad 0..3

    const float* wr = w + (size_t)r * WDIM;

    // ---- zero both LDS tiles (k-pad slots 26..31 must be 0), barrier ----
    {
        int* Ai = (int*)Als;
        for (int g = tid; g < HH * 16; g += NTHREADS) Ai[g] = 0;
        int* Xi = (int*)xls;
        for (int g = tid; g < XTILE * 16; g += NTHREADS) Xi[g] = 0;
    }
    __syncthreads();
    // stage w1 (bf16, k-duplicated: slots [0..12] and [13..25])
    for (int g = tid; g < W1DIM; g += NTHREADS) {
        int h = g / IND;
        int i = g - h * IND;
        short b = f2bf(wr[g]);
        Als[h * 32 + i] = b;        // k = i       (pairs with x_hi)
        Als[h * 32 + 13 + i] = b;   // k = 13 + i  (pairs with x_lo)
    }
    // stage w2 (fp32)
    for (int g = tid; g < HH; g += NTHREADS) w2s[g] = wr[W1DIM + g];
    // stage x tile (hi/lo split, divergence-free, coalesced global reads)
    {
        const float* xblk = x + (size_t)blockIdx.x * XTILE * IND;
        for (int g = tid; g < XTILE * IND; g += NTHREADS) {
            int nl = g / IND;
            int i = g - nl * IND;
            float v = xblk[g];
            short hs = f2bf(v);
            short ls = f2bf(v - bf2f(hs));
            xls[nl * 32 + i] = hs;        // k = i       (x_hi)
            xls[nl * 32 + 13 + i] = ls;   // k = 13 + i  (x_lo)
        }
    }
    __syncthreads();

    // ---- fetch this wave's 8 B-frags from LDS (broadcast b128, no divergence) ----
    const int nb = blockIdx.x * XTILE + wave * 128;
    short8 bfrag[8];
#pragma unroll
    for (int nt = 0; nt < 8; ++nt) {
        bfrag[nt] = *(const short8*)&xls[(wave * 128 + nt * 16 + m) * 32 + q * 8];
    }

    float mu[8];
#pragma unroll
    for (int i = 0; i < 8; ++i) mu[i] = 0.0f;

    // ---- main loop: 32 h-tiles; A-frag + w2 shared across 8 n-tile MFMAs ----
#pragma unroll 2
    for (int t = 0; t < 32; ++t) {
        const short8 a = *(const short8*)&Als[(t * 16 + m) * 32 + q * 8];
        const f32x4 wv = *(const f32x4*)&w2s[t * 16 + q * 4];
#pragma unroll
        for (int nt = 0; nt < 8; ++nt) {
            f32x4 c = {0.0f, 0.0f, 0.0f, 0.0f};
            c = __builtin_amdgcn_mfma_f32_16x16x32_bf16(a, bfrag[nt], c, 0, 0, 0);
            // C layout: col n = lane&15, row h = t*16 + q*4 + reg
            mu[nt] = fmaf(fmaxf(c[0], 0.0f), wv[0], mu[nt]);
            mu[nt] = fmaf(fmaxf(c[1], 0.0f), wv[1], mu[nt]);
            mu[nt] = fmaf(fmaxf(c[2], 0.0f), wv[2], mu[nt]);
            mu[nt] = fmaf(fmaxf(c[3], 0.0f), wv[3], mu[nt]);
        }
    }

    // ---- reduce partial mu across quads (butterfly: every lane gets full sum) ----
#pragma unroll
    for (int nt = 0; nt < 8; ++nt) {
        float v = mu[nt];
        v += __shfl_xor(v, 16, 64);
        v += __shfl_xor(v, 32, 64);
        mu[nt] = v;
    }

    // lane stores n = nb + s*64 + lane  (s=0,1) -> needs nt = q + 4s
    float mu0, mu1;
    if (q == 0)      { mu0 = mu[0]; mu1 = mu[4]; }
    else if (q == 1) { mu0 = mu[1]; mu1 = mu[5]; }
    else if (q == 2) { mu0 = mu[2]; mu1 = mu[6]; }
    else             { mu0 = mu[3]; mu1 = mu[7]; }

    int n0 = nb + lane;
    float resid0 = y[n0] - mu0;
    out[(size_t)r * NN + n0] = fmaf(-0.5f * resid0, resid0, NEG_HALF_LOG_2PI);
    int n1 = nb + 64 + lane;
    float resid1 = y[n1] - mu1;
    out[(size_t)r * NN + n1] = fmaf(-0.5f * resid1, resid1, NEG_HALF_LOG_2PI);
}

extern "C" void kernel_launch(void* const* d_in, const int* in_sizes, int n_in,
                              void* d_out, int out_size, void* d_ws, size_t ws_size,
                              hipStream_t stream) {
    const float* x = (const float*)d_in[0];   // [N, 13]
    const float* y = (const float*)d_in[1];   // [N, 1]
    const float* w = (const float*)d_in[2];   // [R, 7168]
    float* out = (float*)d_out;               // [R, N]

    dim3 grid(NN / XTILE, RR);   // (4, 256) = 1024 blocks, 4 waves each
    dim3 block(NTHREADS);
    ffrelu_mfma_kernel<<<grid, block, 0, stream>>>(x, y, w, out);
}

// Round 10
// 105.407 us; speedup vs baseline: 1.1483x; 1.1483x over previous
//
#include <hip/hip_runtime.h>

#define HH 512
#define IND 13
#define NN 2048
#define RR 256
#define WDIM 7168      // (13+1)*512
#define W1DIM 6656     // 13*512
#define NTHREADS 256
#define NEG_HALF_LOG_2PI (-0.91893853320467274f)

typedef __attribute__((ext_vector_type(8))) short short8;   // 8 bf16 (4 VGPRs) MFMA A/B frag
typedef __attribute__((ext_vector_type(4))) float f32x4;    // MFMA C/D frag

// fp32 -> bf16 round-to-nearest-even (bit pattern)
__device__ __forceinline__ short f2bf(float f) {
    unsigned u = __float_as_uint(f);
    u += 0x7fffu + ((u >> 16) & 1u);
    return (short)(u >> 16);
}
__device__ __forceinline__ float bf2f(short s) {
    return __uint_as_float(((unsigned)(unsigned short)s) << 16);
}

// Per block: one r, 512 n (4 waves x 128 n). Per wave: 32 h-tiles x 8 n-tiles of
// 16x16x32 bf16 MFMA, hidden stays in C-frags, relu+w2-dot in fp32 VALU.
// K packing: A = [w1(13) | w1(13) | 0(6)], B = [x_hi(13) | x_lo(13) | 0(6)]
// => hidden = w1_bf16 . x_fp32 (x split exact); only w1 carries bf16 rounding.
// R10 delta vs green R8 (ONLY change): grid roles swapped -> r = blockIdx.x
// (fast dim). The 4 blocks sharing w[r] get IDs r, 256+r, 512+r, 768+r; with
// round-robin XCD placement (256 % 8 == 0) they land on the SAME XCD, so w[r]
// is HBM-fetched once and L2-hit by the other three (R8: 4 different XCDs,
// FETCH_SIZE 2x ideal, ~900-cyc prologue stalls). Outputs bitwise identical.
__global__ __launch_bounds__(NTHREADS, 3)
void ffrelu_mfma_kernel(const float* __restrict__ x,
                        const float* __restrict__ y,
                        const float* __restrict__ w,
                        float* __restrict__ out) {
    __shared__ short Als[HH * 32];   // 32768 B
    __shared__ float w2s[HH];        // 2048 B, kept fp32

    const int tid = threadIdx.x;
    const int r = blockIdx.x;       // fast dim: same-r blocks -> same XCD
    const int wave = tid >> 6;
    const int lane = tid & 63;
    const int m = lane & 15;        // MFMA row/col index within 16
    const int q = lane >> 4;        // quad 0..3

    const float* wr = w + (size_t)r * WDIM;

    // ---- zero A (k-pad slots 26..31 must be 0), then stage w1 (bf16, k-duplicated) + w2 (fp32) ----
    int* Ai = (int*)Als;
    for (int g = tid; g < HH * 16; g += NTHREADS) Ai[g] = 0;
    __syncthreads();
    for (int g = tid; g < W1DIM; g += NTHREADS) {
        int h = g / IND;
        int i = g - h * IND;
        short b = f2bf(wr[g]);
        Als[h * 32 + i] = b;        // k = i       (pairs with x_hi)
        Als[h * 32 + 13 + i] = b;   // k = 13 + i  (pairs with x_lo)
    }
    for (int g = tid; g < HH; g += NTHREADS) w2s[g] = wr[W1DIM + g];
    __syncthreads();

    // ---- build 8 B-frags from x (hi/lo split), register-resident for whole kernel ----
    const int nb = blockIdx.y * 512 + wave * 128;
    short8 bfrag[8];
#pragma unroll
    for (int nt = 0; nt < 8; ++nt) {
        const float* xp = x + (size_t)(nb + nt * 16 + m) * IND;
        float v[13]; short hs[13], ls[13];
#pragma unroll
        for (int i = 0; i < 13; ++i) {
            v[i] = xp[i];
            hs[i] = f2bf(v[i]);
            ls[i] = f2bf(v[i] - bf2f(hs[i]));
        }
        short8 b;
        if (q == 0) {
            b[0]=hs[0]; b[1]=hs[1]; b[2]=hs[2]; b[3]=hs[3];
            b[4]=hs[4]; b[5]=hs[5]; b[6]=hs[6]; b[7]=hs[7];
        } else if (q == 1) {
            b[0]=hs[8]; b[1]=hs[9]; b[2]=hs[10]; b[3]=hs[11];
            b[4]=hs[12]; b[5]=ls[0]; b[6]=ls[1]; b[7]=ls[2];
        } else if (q == 2) {
            b[0]=ls[3]; b[1]=ls[4]; b[2]=ls[5]; b[3]=ls[6];
            b[4]=ls[7]; b[5]=ls[8]; b[6]=ls[9]; b[7]=ls[10];
        } else {
            b[0]=ls[11]; b[1]=ls[12]; b[2]=0; b[3]=0;
            b[4]=0; b[5]=0; b[6]=0; b[7]=0;
        }
        bfrag[nt] = b;
    }

    float mu[8];
#pragma unroll
    for (int i = 0; i < 8; ++i) mu[i] = 0.0f;

    // ---- main loop: 32 h-tiles; A-frag + w2 shared across 8 n-tile MFMAs ----
#pragma unroll 2
    for (int t = 0; t < 32; ++t) {
        const short8 a = *(const short8*)&Als[(t * 16 + m) * 32 + q * 8];
        const f32x4 wv = *(const f32x4*)&w2s[t * 16 + q * 4];
#pragma unroll
        for (int nt = 0; nt < 8; ++nt) {
            f32x4 c = {0.0f, 0.0f, 0.0f, 0.0f};
            c = __builtin_amdgcn_mfma_f32_16x16x32_bf16(a, bfrag[nt], c, 0, 0, 0);
            // C layout: col n = lane&15, row h = t*16 + q*4 + reg
            mu[nt] = fmaf(fmaxf(c[0], 0.0f), wv[0], mu[nt]);
            mu[nt] = fmaf(fmaxf(c[1], 0.0f), wv[1], mu[nt]);
            mu[nt] = fmaf(fmaxf(c[2], 0.0f), wv[2], mu[nt]);
            mu[nt] = fmaf(fmaxf(c[3], 0.0f), wv[3], mu[nt]);
        }
    }

    // ---- reduce partial mu across quads (butterfly: every lane gets full sum) ----
#pragma unroll
    for (int nt = 0; nt < 8; ++nt) {
        float v = mu[nt];
        v += __shfl_xor(v, 16, 64);
        v += __shfl_xor(v, 32, 64);
        mu[nt] = v;
    }

    // lane stores n = nb + s*64 + lane  (s=0,1) -> needs nt = q + 4s
    float mu0, mu1;
    if (q == 0)      { mu0 = mu[0]; mu1 = mu[4]; }
    else if (q == 1) { mu0 = mu[1]; mu1 = mu[5]; }
    else if (q == 2) { mu0 = mu[2]; mu1 = mu[6]; }
    else             { mu0 = mu[3]; mu1 = mu[7]; }

    int n0 = nb + lane;
    float resid0 = y[n0] - mu0;
    out[(size_t)r * NN + n0] = fmaf(-0.5f * resid0, resid0, NEG_HALF_LOG_2PI);
    int n1 = nb + 64 + lane;
    float resid1 = y[n1] - mu1;
    out[(size_t)r * NN + n1] = fmaf(-0.5f * resid1, resid1, NEG_HALF_LOG_2PI);
}

extern "C" void kernel_launch(void* const* d_in, const int* in_sizes, int n_in,
                              void* d_out, int out_size, void* d_ws, size_t ws_size,
                              hipStream_t stream) {
    const float* x = (const float*)d_in[0];   // [N, 13]
    const float* y = (const float*)d_in[1];   // [N, 1]
    const float* w = (const float*)d_in[2];   // [R, 7168]
    float* out = (float*)d_out;               // [R, N]

    dim3 grid(RR, NN / 512);   // (256, 4): r is the FAST dim -> same-r on same XCD
    dim3 block(NTHREADS);
    ffrelu_mfma_kernel<<<grid, block, 0, stream>>>(x, y, w, out);
}

// Round 13
// 104.829 us; speedup vs baseline: 1.1546x; 1.0055x over previous
//
#include <hip/hip_runtime.h>

#define HH 512
#define IND 13
#define NN 2048
#define RR 256
#define WDIM 7168      // (13+1)*512
#define W1DIM 6656     // 13*512
#define XTILE 256      // n per block (4 waves x 64 n) -- THE ONLY R13 DELTA vs R10
#define NTHREADS 256
#define NEG_HALF_LOG_2PI (-0.91893853320467274f)

typedef __attribute__((ext_vector_type(8))) short short8;   // 8 bf16 (4 VGPRs) MFMA A/B frag
typedef __attribute__((ext_vector_type(4))) float f32x4;    // MFMA C/D frag

// fp32 -> bf16 round-to-nearest-even (bit pattern)
__device__ __forceinline__ short f2bf(float f) {
    unsigned u = __float_as_uint(f);
    u += 0x7fffu + ((u >> 16) & 1u);
    return (short)(u >> 16);
}
__device__ __forceinline__ float bf2f(short s) {
    return __uint_as_float(((unsigned)(unsigned short)s) << 16);
}

// R13 = green R10 with ONE delta: XTILE 512 -> 256 (4 n-tiles/wave, one store).
// Purpose: bisect the R11/R12 failure -- (a) 16-short A-packing+no-split vs
// (c)/(d) XTILE-256 tiling/store. This kernel keeps R10's proven numerics
// (dup-w1 32-short A rows, x hi/lo split => only w1 carries bf16 rounding)
// and tests ONLY the tiling/store delta. Note: green rounds' absmax=256.0 is
// the 1-bf16-ulp comparison floor at max|ref|~37683 -- green kernels are exact.
// Grid (256, 8): r fast dim -> same-r blocks share an XCD (R10 win);
// 2048 blocks -> 2 resident rounds/CU -> cross-block prologue/mainloop overlap.
__global__ __launch_bounds__(NTHREADS, 3)
void ffrelu_mfma_kernel(const float* __restrict__ x,
                        const float* __restrict__ y,
                        const float* __restrict__ w,
                        float* __restrict__ out) {
    __shared__ short Als[HH * 32];   // 32768 B: w1 rows [w1(13)|w1(13)|0(6)]
    __shared__ float w2s[HH];        // 2048 B, kept fp32

    const int tid = threadIdx.x;
    const int r = blockIdx.x;       // fast dim: same-r blocks -> same XCD
    const int wave = tid >> 6;
    const int lane = tid & 63;
    const int m = lane & 15;        // MFMA row/col index within 16
    const int q = lane >> 4;        // quad 0..3

    const float* wr = w + (size_t)r * WDIM;

    // ---- zero A (k-pad slots 26..31 must be 0), then stage w1 (bf16, k-duplicated) + w2 (fp32) ----
    int* Ai = (int*)Als;
    for (int g = tid; g < HH * 16; g += NTHREADS) Ai[g] = 0;
    __syncthreads();
    for (int g = tid; g < W1DIM; g += NTHREADS) {
        int h = g / IND;
        int i = g - h * IND;
        short b = f2bf(wr[g]);
        Als[h * 32 + i] = b;        // k = i       (pairs with x_hi)
        Als[h * 32 + 13 + i] = b;   // k = 13 + i  (pairs with x_lo)
    }
    for (int g = tid; g < HH; g += NTHREADS) w2s[g] = wr[W1DIM + g];
    __syncthreads();

    // ---- build 4 B-frags from x (hi/lo split), register-resident ----
    const int nb = blockIdx.y * XTILE + wave * 64;
    short8 bfrag[4];
#pragma unroll
    for (int nt = 0; nt < 4; ++nt) {
        const float* xp = x + (size_t)(nb + nt * 16 + m) * IND;
        float v[13]; short hs[13], ls[13];
#pragma unroll
        for (int i = 0; i < 13; ++i) {
            v[i] = xp[i];
            hs[i] = f2bf(v[i]);
            ls[i] = f2bf(v[i] - bf2f(hs[i]));
        }
        short8 b;
        if (q == 0) {
            b[0]=hs[0]; b[1]=hs[1]; b[2]=hs[2]; b[3]=hs[3];
            b[4]=hs[4]; b[5]=hs[5]; b[6]=hs[6]; b[7]=hs[7];
        } else if (q == 1) {
            b[0]=hs[8]; b[1]=hs[9]; b[2]=hs[10]; b[3]=hs[11];
            b[4]=hs[12]; b[5]=ls[0]; b[6]=ls[1]; b[7]=ls[2];
        } else if (q == 2) {
            b[0]=ls[3]; b[1]=ls[4]; b[2]=ls[5]; b[3]=ls[6];
            b[4]=ls[7]; b[5]=ls[8]; b[6]=ls[9]; b[7]=ls[10];
        } else {
            b[0]=ls[11]; b[1]=ls[12]; b[2]=0; b[3]=0;
            b[4]=0; b[5]=0; b[6]=0; b[7]=0;
        }
        bfrag[nt] = b;
    }

    float mu[4];
#pragma unroll
    for (int i = 0; i < 4; ++i) mu[i] = 0.0f;

    // ---- main loop: 32 h-tiles x 4 n-tiles ----
#pragma unroll 2
    for (int t = 0; t < 32; ++t) {
        const short8 a = *(const short8*)&Als[(t * 16 + m) * 32 + q * 8];
        const f32x4 wv = *(const f32x4*)&w2s[t * 16 + q * 4];
#pragma unroll
        for (int nt = 0; nt < 4; ++nt) {
            f32x4 c = {0.0f, 0.0f, 0.0f, 0.0f};
            c = __builtin_amdgcn_mfma_f32_16x16x32_bf16(a, bfrag[nt], c, 0, 0, 0);
            // C layout: col n = lane&15, row h = t*16 + q*4 + reg
            mu[nt] = fmaf(fmaxf(c[0], 0.0f), wv[0], mu[nt]);
            mu[nt] = fmaf(fmaxf(c[1], 0.0f), wv[1], mu[nt]);
            mu[nt] = fmaf(fmaxf(c[2], 0.0f), wv[2], mu[nt]);
            mu[nt] = fmaf(fmaxf(c[3], 0.0f), wv[3], mu[nt]);
        }
    }

    // ---- reduce partial mu across quads (butterfly: every lane gets full sum) ----
#pragma unroll
    for (int nt = 0; nt < 4; ++nt) {
        float v = mu[nt];
        v += __shfl_xor(v, 16, 64);
        v += __shfl_xor(v, 32, 64);
        mu[nt] = v;
    }

    // lane stores n = nb + lane = nb + q*16 + m -> tile nt=q, col m
    float mu0;
    if (q == 0)      mu0 = mu[0];
    else if (q == 1) mu0 = mu[1];
    else if (q == 2) mu0 = mu[2];
    else             mu0 = mu[3];

    const int n0 = nb + lane;
    float resid0 = y[n0] - mu0;
    out[(size_t)r * NN + n0] = fmaf(-0.5f * resid0, resid0, NEG_HALF_LOG_2PI);
}

extern "C" void kernel_launch(void* const* d_in, const int* in_sizes, int n_in,
                              void* d_out, int out_size, void* d_ws, size_t ws_size,
                              hipStream_t stream) {
    const float* x = (const float*)d_in[0];   // [N, 13]
    const float* y = (const float*)d_in[1];   // [N, 1]
    const float* w = (const float*)d_in[2];   // [R, 7168]
    float* out = (float*)d_out;               // [R, N]

    dim3 grid(RR, NN / XTILE);   // (256, 8): r fast -> same-r blocks share an XCD
    dim3 block(NTHREADS);
    ffrelu_mfma_kernel<<<grid, block, 0, stream>>>(x, y, w, out);
}

// Round 14
// 97.661 us; speedup vs baseline: 1.2393x; 1.0734x over previous
//
#include <hip/hip_runtime.h>

#define HH 512
#define IND 13
#define NN 2048
#define RR 256
#define WDIM 7168      // (13+1)*512
#define W1DIM 6656     // 13*512
#define XTILE 256      // n per block (4 waves x 64 n)
#define NTHREADS 256
#define NEG_HALF_LOG_2PI (-0.91893853320467274f)

typedef __attribute__((ext_vector_type(8))) short short8;   // 8 bf16 (4 VGPRs) MFMA A/B frag
typedef __attribute__((ext_vector_type(4))) float f32x4;    // MFMA C/D frag

// fp32 -> bf16 round-to-nearest-even (bit pattern)
__device__ __forceinline__ short f2bf(float f) {
    unsigned u = __float_as_uint(f);
    u += 0x7fffu + ((u >> 16) & 1u);
    return (short)(u >> 16);
}
__device__ __forceinline__ float bf2f(short s) {
    return __uint_as_float(((unsigned)(unsigned short)s) << 16);
}

// R14 = green R13 with the LDS-halving q-parity scheme:
//   A: single-copy w1 rows, 16 shorts [w1(13)|0(3)]; lane reads offset (q&1)*8
//      -> q0/q2 see w1[0..7], q1/q3 see {w1[8..12],0,0,0}.
//   B: q0/q1 carry x_hi slices, q2/q3 carry x_lo slices (same slice split).
//   Positional pairing => computes exactly w1*x_hi + w1*x_lo (= R13's math).
//   bfrag built BRANCH-FREE (ternaries on fully-defined values): the R11/R12
//   failures are attributed to divergent partial sub-dword writes into short8;
//   no divergent control flow here, no zero*garbage assumption, no tail read.
// LDS 34816 -> 18432 B => 8 blocks/CU (was 4); VGPR ~52 <= 64 keeps 8 waves/EU.
// Grid (256, 8): r fast dim -> same-r blocks share an XCD (R10 win).
__global__ __launch_bounds__(NTHREADS, 3)
void ffrelu_mfma_kernel(const float* __restrict__ x,
                        const float* __restrict__ y,
                        const float* __restrict__ w,
                        float* __restrict__ out) {
    __shared__ short Als[HH * 16];   // 16384 B: w1 rows [w1(13)|0(3)]
    __shared__ float w2s[HH];        // 2048 B, fp32

    const int tid = threadIdx.x;
    const int r = blockIdx.x;       // fast dim: same-r blocks -> same XCD
    const int wave = tid >> 6;
    const int lane = tid & 63;
    const int m = lane & 15;        // MFMA row/col index within 16
    const int q = lane >> 4;        // quad 0..3

    const float* wr = w + (size_t)r * WDIM;

    // ---- zero Als (slots 13..15 of each row must be 0), barrier ----
    {
        int* Ai = (int*)Als;
        for (int g = tid; g < HH * 8; g += NTHREADS) Ai[g] = 0;
    }
    __syncthreads();
    // ---- stage w1 (bf16, single copy) + w2 (fp32) ----
    for (int g = tid; g < W1DIM; g += NTHREADS) {
        int h = g / IND;
        int i = g - h * IND;
        Als[h * 16 + i] = f2bf(wr[g]);
    }
    for (int g = tid; g < HH; g += NTHREADS) w2s[g] = wr[W1DIM + g];
    __syncthreads();

    // ---- build 4 B-frags from x (hi/lo split), BRANCH-FREE ----
    const int nb = blockIdx.y * XTILE + wave * 64;
    const bool lo  = (q >= 2);     // q2/q3 lanes carry x_lo
    const bool hi8 = (q & 1);      // q1/q3 lanes carry slice [8..12]
    short8 bfrag[4];
#pragma unroll
    for (int nt = 0; nt < 4; ++nt) {
        const float* xp = x + (size_t)(nb + nt * 16 + m) * IND;
        short hs[13], ls[13];
#pragma unroll
        for (int i = 0; i < 13; ++i) {
            float v = xp[i];
            hs[i] = f2bf(v);
            ls[i] = f2bf(v - bf2f(hs[i]));
        }
        short s[13];
#pragma unroll
        for (int i = 0; i < 13; ++i) s[i] = lo ? ls[i] : hs[i];
        short8 b;
        b[0] = hi8 ? s[8]        : s[0];
        b[1] = hi8 ? s[9]        : s[1];
        b[2] = hi8 ? s[10]       : s[2];
        b[3] = hi8 ? s[11]       : s[3];
        b[4] = hi8 ? s[12]       : s[4];
        b[5] = hi8 ? (short)0    : s[5];
        b[6] = hi8 ? (short)0    : s[6];
        b[7] = hi8 ? (short)0    : s[7];
        bfrag[nt] = b;
    }

    float mu[4];
#pragma unroll
    for (int i = 0; i < 4; ++i) mu[i] = 0.0f;

    // ---- main loop: 32 h-tiles x 4 n-tiles; A read via q-parity ----
#pragma unroll 2
    for (int t = 0; t < 32; ++t) {
        const short8 a = *(const short8*)&Als[(t * 16 + m) * 16 + (q & 1) * 8];
        const f32x4 wv = *(const f32x4*)&w2s[t * 16 + q * 4];
#pragma unroll
        for (int nt = 0; nt < 4; ++nt) {
            f32x4 c = {0.0f, 0.0f, 0.0f, 0.0f};
            c = __builtin_amdgcn_mfma_f32_16x16x32_bf16(a, bfrag[nt], c, 0, 0, 0);
            // C layout: col n = lane&15, row h = t*16 + q*4 + reg
            mu[nt] = fmaf(fmaxf(c[0], 0.0f), wv[0], mu[nt]);
            mu[nt] = fmaf(fmaxf(c[1], 0.0f), wv[1], mu[nt]);
            mu[nt] = fmaf(fmaxf(c[2], 0.0f), wv[2], mu[nt]);
            mu[nt] = fmaf(fmaxf(c[3], 0.0f), wv[3], mu[nt]);
        }
    }

    // ---- reduce partial mu across quads (butterfly: every lane gets full sum) ----
#pragma unroll
    for (int nt = 0; nt < 4; ++nt) {
        float v = mu[nt];
        v += __shfl_xor(v, 16, 64);
        v += __shfl_xor(v, 32, 64);
        mu[nt] = v;
    }

    // lane stores n = nb + lane = nb + q*16 + m -> tile nt=q, col m
    float mu0;
    if (q == 0)      mu0 = mu[0];
    else if (q == 1) mu0 = mu[1];
    else if (q == 2) mu0 = mu[2];
    else             mu0 = mu[3];

    const int n0 = nb + lane;
    float resid0 = y[n0] - mu0;
    out[(size_t)r * NN + n0] = fmaf(-0.5f * resid0, resid0, NEG_HALF_LOG_2PI);
}

extern "C" void kernel_launch(void* const* d_in, const int* in_sizes, int n_in,
                              void* d_out, int out_size, void* d_ws, size_t ws_size,
                              hipStream_t stream) {
    const float* x = (const float*)d_in[0];   // [N, 13]
    const float* y = (const float*)d_in[1];   // [N, 1]
    const float* w = (const float*)d_in[2];   // [R, 7168]
    float* out = (float*)d_out;               // [R, N]

    dim3 grid(RR, NN / XTILE);   // (256, 8): r fast -> same-r blocks share an XCD
    dim3 block(NTHREADS);
    ffrelu_mfma_kernel<<<grid, block, 0, stream>>>(x, y, w, out);
}

// Round 16
// 96.438 us; speedup vs baseline: 1.2551x; 1.0127x over previous
//
#include <hip/hip_runtime.h>

#define HH 512
#define IND 13
#define NN 2048
#define RR 256
#define WDIM 7168      // (13+1)*512
#define W1DIM 6656     // 13*512
#define XTILE 256      // n per block (4 waves x 64 n)
#define NTHREADS 256
#define NEG_HALF_LOG_2PI (-0.91893853320467274f)

typedef __attribute__((ext_vector_type(8))) short short8;   // 8 bf16 (4 VGPRs) MFMA A/B frag
typedef __attribute__((ext_vector_type(4))) float f32x4;    // MFMA C/D frag
typedef __attribute__((ext_vector_type(2))) float f32x2;    // packed-math pair (v_pk_*_f32)

// fp32 -> bf16 round-to-nearest-even (bit pattern)
__device__ __forceinline__ short f2bf(float f) {
    unsigned u = __float_as_uint(f);
    u += 0x7fffu + ((u >> 16) & 1u);
    return (short)(u >> 16);
}
__device__ __forceinline__ float bf2f(short s) {
    return __uint_as_float(((unsigned)(unsigned short)s) << 16);
}

// R16 = green R14 with ONE delta: the relu+w2-dot epilogue uses 2-wide packed
// fp32 (f32x2 -> v_pk_max_f32 / v_pk_fma_f32), halving main-loop VALU issue
// (8 scalar ops -> 2 pk_max + 2 pk_fma per MFMA). Accumulators are f32x2,
// horizontally summed once before the quad butterfly (fp32 order change only).
// NOTE (session ledger): relu-split formulations are BANNED (3/3 failed:
// R3 1152, R4 1248, R15 2176); divergent partial short8 writes BANNED
// (R11/R12); direct-relu + branch-free frag builds are the proven-green path.
// Structure from R14: one r x 256 n per block (4 waves x 64 n); single-copy
// 16-short w1 rows with q-parity A reads; x hi/lo split across q-halves;
// LDS 18432 B -> 8 blocks/CU; grid (256,8) r-fast (XCD locality, R10).
__global__ __launch_bounds__(NTHREADS, 3)
void ffrelu_mfma_kernel(const float* __restrict__ x,
                        const float* __restrict__ y,
                        const float* __restrict__ w,
                        float* __restrict__ out) {
    __shared__ short Als[HH * 16];   // 16384 B: w1 rows [w1(13)|0(3)]
    __shared__ float w2s[HH];        // 2048 B, fp32

    const int tid = threadIdx.x;
    const int r = blockIdx.x;       // fast dim: same-r blocks -> same XCD
    const int wave = tid >> 6;
    const int lane = tid & 63;
    const int m = lane & 15;        // MFMA row/col index within 16
    const int q = lane >> 4;        // quad 0..3

    const float* wr = w + (size_t)r * WDIM;

    // ---- zero Als (slots 13..15 of each row must be 0), barrier ----
    {
        int* Ai = (int*)Als;
        for (int g = tid; g < HH * 8; g += NTHREADS) Ai[g] = 0;
    }
    __syncthreads();
    // ---- stage w1 (bf16, single copy) + w2 (fp32) ----
    for (int g = tid; g < W1DIM; g += NTHREADS) {
        int h = g / IND;
        int i = g - h * IND;
        Als[h * 16 + i] = f2bf(wr[g]);
    }
    for (int g = tid; g < HH; g += NTHREADS) w2s[g] = wr[W1DIM + g];
    __syncthreads();

    // ---- build 4 B-frags from x (hi/lo split), BRANCH-FREE (R14 verbatim) ----
    const int nb = blockIdx.y * XTILE + wave * 64;
    const bool lo  = (q >= 2);     // q2/q3 lanes carry x_lo
    const bool hi8 = (q & 1);      // q1/q3 lanes carry slice [8..12]
    short8 bfrag[4];
#pragma unroll
    for (int nt = 0; nt < 4; ++nt) {
        const float* xp = x + (size_t)(nb + nt * 16 + m) * IND;
        short hs[13], ls[13];
#pragma unroll
        for (int i = 0; i < 13; ++i) {
            float v = xp[i];
            hs[i] = f2bf(v);
            ls[i] = f2bf(v - bf2f(hs[i]));
        }
        short s[13];
#pragma unroll
        for (int i = 0; i < 13; ++i) s[i] = lo ? ls[i] : hs[i];
        short8 b;
        b[0] = hi8 ? s[8]        : s[0];
        b[1] = hi8 ? s[9]        : s[1];
        b[2] = hi8 ? s[10]       : s[2];
        b[3] = hi8 ? s[11]       : s[3];
        b[4] = hi8 ? s[12]       : s[4];
        b[5] = hi8 ? (short)0    : s[5];
        b[6] = hi8 ? (short)0    : s[6];
        b[7] = hi8 ? (short)0    : s[7];
        bfrag[nt] = b;
    }

    // packed accumulators: muv[nt][0] covers regs {0,1}, muv[nt][1] regs {2,3}
    f32x2 muv[4][2];
#pragma unroll
    for (int i = 0; i < 4; ++i) {
        muv[i][0] = (f32x2){0.0f, 0.0f};
        muv[i][1] = (f32x2){0.0f, 0.0f};
    }
    const f32x2 zero2 = {0.0f, 0.0f};

    // ---- main loop: 32 h-tiles x 4 n-tiles; packed relu+dot ----
#pragma unroll 2
    for (int t = 0; t < 32; ++t) {
        const short8 a = *(const short8*)&Als[(t * 16 + m) * 16 + (q & 1) * 8];
        const f32x4 wv = *(const f32x4*)&w2s[t * 16 + q * 4];
        const f32x2 wv01 = {wv[0], wv[1]};
        const f32x2 wv23 = {wv[2], wv[3]};
#pragma unroll
        for (int nt = 0; nt < 4; ++nt) {
            f32x4 c = {0.0f, 0.0f, 0.0f, 0.0f};
            c = __builtin_amdgcn_mfma_f32_16x16x32_bf16(a, bfrag[nt], c, 0, 0, 0);
            // C layout: col n = lane&15, row h = t*16 + q*4 + reg
            f32x2 c01 = {c[0], c[1]};
            f32x2 c23 = {c[2], c[3]};
            c01 = __builtin_elementwise_max(c01, zero2);   // v_pk_max_f32
            c23 = __builtin_elementwise_max(c23, zero2);
            muv[nt][0] += c01 * wv01;                      // v_pk_fma_f32
            muv[nt][1] += c23 * wv23;
        }
    }

    // ---- horizontal sum + reduce across quads (butterfly) ----
    float mu[4];
#pragma unroll
    for (int nt = 0; nt < 4; ++nt) {
        f32x2 p = muv[nt][0] + muv[nt][1];
        float v = p[0] + p[1];
        v += __shfl_xor(v, 16, 64);
        v += __shfl_xor(v, 32, 64);
        mu[nt] = v;
    }

    // lane stores n = nb + lane = nb + q*16 + m -> tile nt=q, col m
    float mu0;
    if (q == 0)      mu0 = mu[0];
    else if (q == 1) mu0 = mu[1];
    else if (q == 2) mu0 = mu[2];
    else             mu0 = mu[3];

    const int n0 = nb + lane;
    float resid0 = y[n0] - mu0;
    out[(size_t)r * NN + n0] = fmaf(-0.5f * resid0, resid0, NEG_HALF_LOG_2PI);
}

extern "C" void kernel_launch(void* const* d_in, const int* in_sizes, int n_in,
                              void* d_out, int out_size, void* d_ws, size_t ws_size,
                              hipStream_t stream) {
    const float* x = (const float*)d_in[0];   // [N, 13]
    const float* y = (const float*)d_in[1];   // [N, 1]
    const float* w = (const float*)d_in[2];   // [R, 7168]
    float* out = (float*)d_out;               // [R, N]

    dim3 grid(RR, NN / XTILE);   // (256, 8): r fast -> same-r blocks share an XCD
    dim3 block(NTHREADS);
    ffrelu_mfma_kernel<<<grid, block, 0, stream>>>(x, y, w, out);
}

// Round 17
// 92.589 us; speedup vs baseline: 1.3072x; 1.0416x over previous
//
#include <hip/hip_runtime.h>

#define HH 512
#define IND 13
#define NN 2048
#define RR 256
#define WDIM 7168      // (13+1)*512
#define W1DIM 6656     // 13*512
#define NBLK 512       // n per block (2 halves x 4 waves x 64 n)
#define NTHREADS 256
#define NEG_HALF_LOG_2PI (-0.91893853320467274f)

typedef __attribute__((ext_vector_type(8))) short short8;   // 8 bf16 (4 VGPRs) MFMA A/B frag
typedef __attribute__((ext_vector_type(4))) float f32x4;    // MFMA C/D frag
typedef __attribute__((ext_vector_type(2))) float f32x2;    // packed-math pair

// fp32 -> bf16 round-to-nearest-even (bit pattern) -- used for w1 (error-dominant term)
__device__ __forceinline__ short f2bf(float f) {
    unsigned u = __float_as_uint(f);
    u += 0x7fffu + ((u >> 16) & 1u);
    return (short)(u >> 16);
}

// R17 = green R16 + prologue diet (R16 post-mortem: VALU ~4200 instr/wave,
// main loop only ~640 -- the prologue dominates):
//  1. 512 n per block as TWO 256-n halves reusing staged w1 (grid (256,4)):
//     staging cost amortized 2x.
//  2. bfrag hi/lo split via TRUNCATION relayout (hs=u>>16; res=x-hi exact;
//     ls=res>>16): 4 ops/elem vs 13 for RNE+sub+RNE. x-repr error ~2^-14 rel,
//     negligible vs w1's 2^-8 RNE (w1 keeps RNE f2bf).
//  3. Div-free staging: thread owns rows 2*tid,2*tid+1, compile-time cols,
//     pads written inline (no zero pass, single barrier), vector row writes.
// Ledger: relu-split BANNED (R3/R4/R15); divergent partial short8 writes
// BANNED (R11/R12); direct relu + branch-free builds = proven-green.
// Structure: single-copy 16-short w1 rows, q-parity A reads, x hi/lo across
// q-halves, LDS 18432 B (8 blocks/CU), grid (256,4) r-fast (XCD locality).
__global__ __launch_bounds__(NTHREADS, 3)
void ffrelu_mfma_kernel(const float* __restrict__ x,
                        const float* __restrict__ y,
                        const float* __restrict__ w,
                        float* __restrict__ out) {
    __shared__ short Als[HH * 16];   // 16384 B: w1 rows [w1(13)|0(3)]
    __shared__ float w2s[HH];        // 2048 B, fp32

    const int tid = threadIdx.x;
    const int r = blockIdx.x;       // fast dim: same-r blocks -> same XCD
    const int wave = tid >> 6;
    const int lane = tid & 63;
    const int m = lane & 15;        // MFMA row/col index within 16
    const int q = lane >> 4;        // quad 0..3

    const float* wr = w + (size_t)r * WDIM;

    // ---- stage w1 (bf16 RNE, 2 rows/thread, pads inline) + w2; ONE barrier ----
#pragma unroll
    for (int rr = 0; rr < 2; ++rr) {
        const int h = tid * 2 + rr;
        const float* p = wr + (size_t)h * IND;
        short tmp[16];
#pragma unroll
        for (int i = 0; i < 13; ++i) tmp[i] = f2bf(p[i]);
        tmp[13] = 0; tmp[14] = 0; tmp[15] = 0;
        *(short8*)&Als[h * 16]     = *(short8*)&tmp[0];
        *(short8*)&Als[h * 16 + 8] = *(short8*)&tmp[8];
    }
    w2s[tid]       = wr[W1DIM + tid];
    w2s[tid + 256] = wr[W1DIM + tid + 256];
    __syncthreads();

    const bool lo  = (q >= 2);     // q2/q3 lanes carry x_lo
    const bool hi8 = (q & 1);      // q1/q3 lanes carry slice [8..12]
    const f32x2 zero2 = {0.0f, 0.0f};

    // ---- two 256-n halves per block, reusing staged w1 ----
    for (int half = 0; half < 2; ++half) {
        const int nb = blockIdx.y * NBLK + half * 256 + wave * 64;

        // -- build 4 B-frags: branch-free truncation hi/lo split --
        short8 bfrag[4];
#pragma unroll
        for (int nt = 0; nt < 4; ++nt) {
            const float* xp = x + (size_t)(nb + nt * 16 + m) * IND;
            short hs[13], ls[13];
#pragma unroll
            for (int i = 0; i < 13; ++i) {
                float v = xp[i];
                unsigned u = __float_as_uint(v);
                hs[i] = (short)(u >> 16);                       // truncate to bf16
                float res = v - __uint_as_float(u & 0xffff0000u); // exact remainder
                ls[i] = (short)(__float_as_uint(res) >> 16);     // truncate remainder
            }
            short s[13];
#pragma unroll
            for (int i = 0; i < 13; ++i) s[i] = lo ? ls[i] : hs[i];
            short8 b;
            b[0] = hi8 ? s[8]     : s[0];
            b[1] = hi8 ? s[9]     : s[1];
            b[2] = hi8 ? s[10]    : s[2];
            b[3] = hi8 ? s[11]    : s[3];
            b[4] = hi8 ? s[12]    : s[4];
            b[5] = hi8 ? (short)0 : s[5];
            b[6] = hi8 ? (short)0 : s[6];
            b[7] = hi8 ? (short)0 : s[7];
            bfrag[nt] = b;
        }

        // packed accumulators: muv[nt][0] covers regs {0,1}, muv[nt][1] regs {2,3}
        f32x2 muv[4][2];
#pragma unroll
        for (int i = 0; i < 4; ++i) {
            muv[i][0] = zero2;
            muv[i][1] = zero2;
        }

        // -- main loop: 32 h-tiles x 4 n-tiles; packed relu+dot --
#pragma unroll 2
        for (int t = 0; t < 32; ++t) {
            const short8 a = *(const short8*)&Als[(t * 16 + m) * 16 + (q & 1) * 8];
            const f32x4 wv = *(const f32x4*)&w2s[t * 16 + q * 4];
            const f32x2 wv01 = {wv[0], wv[1]};
            const f32x2 wv23 = {wv[2], wv[3]};
#pragma unroll
            for (int nt = 0; nt < 4; ++nt) {
                f32x4 c = {0.0f, 0.0f, 0.0f, 0.0f};
                c = __builtin_amdgcn_mfma_f32_16x16x32_bf16(a, bfrag[nt], c, 0, 0, 0);
                // C layout: col n = lane&15, row h = t*16 + q*4 + reg
                f32x2 c01 = {c[0], c[1]};
                f32x2 c23 = {c[2], c[3]};
                c01 = __builtin_elementwise_max(c01, zero2);
                c23 = __builtin_elementwise_max(c23, zero2);
                muv[nt][0] += c01 * wv01;
                muv[nt][1] += c23 * wv23;
            }
        }

        // -- horizontal sum + quad butterfly + store --
        float mu[4];
#pragma unroll
        for (int nt = 0; nt < 4; ++nt) {
            f32x2 p = muv[nt][0] + muv[nt][1];
            float v = p[0] + p[1];
            v += __shfl_xor(v, 16, 64);
            v += __shfl_xor(v, 32, 64);
            mu[nt] = v;
        }

        float mu0;
        if (q == 0)      mu0 = mu[0];
        else if (q == 1) mu0 = mu[1];
        else if (q == 2) mu0 = mu[2];
        else             mu0 = mu[3];

        const int n0 = nb + lane;
        float resid0 = y[n0] - mu0;
        out[(size_t)r * NN + n0] = fmaf(-0.5f * resid0, resid0, NEG_HALF_LOG_2PI);
    }
}

extern "C" void kernel_launch(void* const* d_in, const int* in_sizes, int n_in,
                              void* d_out, int out_size, void* d_ws, size_t ws_size,
                              hipStream_t stream) {
    const float* x = (const float*)d_in[0];   // [N, 13]
    const float* y = (const float*)d_in[1];   // [N, 1]
    const float* w = (const float*)d_in[2];   // [R, 7168]
    float* out = (float*)d_out;               // [R, N]

    dim3 grid(RR, NN / NBLK);   // (256, 4): r fast -> same-r blocks share an XCD
    dim3 block(NTHREADS);
    ffrelu_mfma_kernel<<<grid, block, 0, stream>>>(x, y, w, out);
}